// Round 6
// baseline (1114.816 us; speedup 1.0000x reference)
//
#include <hip/hip_runtime.h>
#include <stdint.h>

#define CIN  16
#define COUT 32
#define K2   9

typedef __attribute__((ext_vector_type(8)))  short bf16x8;   // 8 bf16 = 4 VGPR (MFMA A/B frag)
typedef __attribute__((ext_vector_type(16))) float f32x16;   // MFMA 32x32 C/D frag
typedef __attribute__((ext_vector_type(4)))  float f32x4;

// ---------- bf16 helpers (RNE) ----------
__device__ __forceinline__ uint16_t f2bf(float f) {
    union { float f; uint32_t u; } a; a.f = f;
    uint32_t u = a.u;
    uint32_t r = u + 0x7FFFu + ((u >> 16) & 1u);
    return (uint16_t)(r >> 16);
}
__device__ __forceinline__ float bf2f(uint32_t b16) {
    union { uint32_t u; float f; } a; a.u = b16 << 16; return a.f;
}

// ---------- mask-width detection (proven on this harness) ----------
__global__ void detect_mask_kernel(const uint32_t* __restrict__ mw,
                                   int* __restrict__ flag, int n) {
    int t = threadIdx.x;
    uint32_t w = mw[(size_t)4 * (size_t)n + (size_t)t];
    unsigned long long b = __ballot(w == 1u);
    if (t == 0) *flag = (b == ~0ull) ? 1 : 0;
}

// ---------- conv1 + relu -> h (bf16) ----------
// 32-voxel tile per wave. All 9 x-row gathers issued UNCONDITIONALLY (nbr_idx
// is always in [0,N)); mask applied afterwards on the values (off the address
// critical path). Next-tile indices prefetched during the convert+MFMA phase.
// waves_per_eu(3,4): VGPR cap 170 so all 18 gather destinations stay live.
// A-frag: lane l holds A[row=l&31][k=8*(l>>5)+e]; C/D: col=lane&31,
// row=(reg&3)+8*(reg>>2)+4*(lane>>5). (Layouts harness-verified.)
__attribute__((amdgpu_waves_per_eu(3, 4)))
__global__ void __launch_bounds__(256)
conv1_kernel(const float* __restrict__ x,
             const float* __restrict__ W1,
             const float* __restrict__ b1,
             const int*   __restrict__ nidx,
             const void*  __restrict__ nmask,
             const int*   __restrict__ mflag,
             uint16_t*    __restrict__ hbuf,
             int n)
{
    __shared__ __align__(16) uint16_t smw[K2 * 2 * 32 * 8];   // [k][half][col][e]

    for (int i = threadIdx.x; i < K2 * 2 * 32 * 8; i += 256) {
        const int e = i & 7, c2 = (i >> 3) & 31, hf = (i >> 8) & 1, k = i >> 9;
        smw[i] = f2bf(W1[k * (CIN * COUT) + (hf * 8 + e) * COUT + c2]);
    }
    __syncthreads();

    const int lane = threadIdx.x & 63;
    const int wid  = threadIdx.x >> 6;
    const int col  = lane & 31;
    const int half = lane >> 5;
    const int mode32 = *mflag;
    const int*     m32 = (const int*)nmask;
    const uint8_t* m8  = (const uint8_t*)nmask;
    const float bias = b1[col];

    const int ntiles = (n + 31) >> 5;
    const int stride = gridDim.x * 4;
    int p = blockIdx.x * 4 + wid;
    if (p >= ntiles) return;

    int ci[K2];
    {
        const int vc = min((p << 5) + col, n - 1);
        #pragma unroll
        for (int k = 0; k < K2; ++k)
            ci[k] = __builtin_nontemporal_load(nidx + (size_t)k * n + vc);
    }

    for (;;) {
        const int vbase = p << 5;
        const int vc = min(vbase + col, n - 1);

        // issue all 9 x-row gathers (18 x 16B) unconditionally
        f32x4 ga[K2], gb[K2];
        #pragma unroll
        for (int k = 0; k < K2; ++k) {
            const f32x4* pg = (const f32x4*)(x + (size_t)(uint32_t)ci[k] * CIN + half * 8);
            ga[k] = pg[0];
            gb[k] = pg[1];
        }

        // masks load concurrently with the gathers (not on the address path)
        int mk[K2];
        #pragma unroll
        for (int k = 0; k < K2; ++k) {
            const size_t e = (size_t)k * n + (size_t)vc;
            mk[k] = mode32 ? __builtin_nontemporal_load(m32 + e)
                           : (int)__builtin_nontemporal_load(m8 + e);
        }

        // prefetch next-tile indices into ci (dead after gather issue above)
        const int pn = p + stride;
        {
            const int pc = (pn < ntiles) ? pn : p;
            const int wc = min((pc << 5) + col, n - 1);
            #pragma unroll
            for (int k = 0; k < K2; ++k)
                ci[k] = __builtin_nontemporal_load(nidx + (size_t)k * n + wc);
        }

        f32x16 acc = {};
        #pragma unroll
        for (int k = 0; k < K2; ++k) {
            const bf16x8 Bf = *(const bf16x8*)&smw[((k * 2 + half) * 32 + col) * 8];
            const bool m = mk[k] != 0;
            bf16x8 hi, lo;
            #pragma unroll
            for (int e = 0; e < 8; ++e) {
                float xv = (e < 4) ? ga[k][e] : gb[k][e - 4];
                xv = m ? xv : 0.0f;
                const uint16_t hb = f2bf(xv);
                hi[e] = (short)hb;
                lo[e] = (short)f2bf(xv - bf2f(hb));
            }
            acc = __builtin_amdgcn_mfma_f32_32x32x16_bf16(hi, Bf, acc, 0, 0, 0);
            acc = __builtin_amdgcn_mfma_f32_32x32x16_bf16(lo, Bf, acc, 0, 0, 0);
        }

        #pragma unroll
        for (int r = 0; r < 16; ++r) {
            const int row = (r & 3) + 8 * (r >> 2) + 4 * half;
            const int vo = vbase + row;
            if (vo < n)
                hbuf[(size_t)vo * COUT + col] = f2bf(fmaxf(acc[r] + bias, 0.0f));
        }

        if (pn >= ntiles) break;
        p = pn;
    }
}

// ---------- conv2 + residual proj + relu -> out ----------
// Same structure; h-row gathers (64B bf16) land directly in A-frags,
// unconditional issue + cndmask on the fragments.
__attribute__((amdgpu_waves_per_eu(3, 4)))
__global__ void __launch_bounds__(256)
conv2_kernel(const float* __restrict__ x,
             const float* __restrict__ W2,
             const float* __restrict__ b2,
             const float* __restrict__ Wp,
             const float* __restrict__ bp,
             const int*   __restrict__ nidx,
             const void*  __restrict__ nmask,
             const int*   __restrict__ mflag,
             const uint16_t* __restrict__ hbuf,
             float*       __restrict__ out,
             int n)
{
    // [k][cb][half][col][e] for W2 (9216 halfwords), then [half][col][e] for Wp
    __shared__ __align__(16) uint16_t smw[K2 * 4 * 32 * 8 + 2 * 32 * 8];

    for (int i = threadIdx.x; i < K2 * 4 * 32 * 8 + 2 * 32 * 8; i += 256) {
        uint16_t v;
        if (i < K2 * 4 * 32 * 8) {
            const int e = i & 7, c2 = (i >> 3) & 31, hf = (i >> 8) & 1,
                      cb = (i >> 9) & 1, k = i >> 10;
            v = f2bf(W2[k * (COUT * COUT) + (cb * 16 + hf * 8 + e) * COUT + c2]);
        } else {
            const int j = i - K2 * 4 * 32 * 8;
            const int e = j & 7, c2 = (j >> 3) & 31, hf = (j >> 8) & 1;
            v = f2bf(Wp[(hf * 8 + e) * COUT + c2]);
        }
        smw[i] = v;
    }
    __syncthreads();

    const int lane = threadIdx.x & 63;
    const int wid  = threadIdx.x >> 6;
    const int col  = lane & 31;
    const int half = lane >> 5;
    const int mode32 = *mflag;
    const int*     m32 = (const int*)nmask;
    const uint8_t* m8  = (const uint8_t*)nmask;
    const float bias = b2[col] + bp[col];

    const int ntiles = (n + 31) >> 5;
    const int stride = gridDim.x * 4;
    int p = blockIdx.x * 4 + wid;
    if (p >= ntiles) return;

    int ci[K2];
    {
        const int vc = min((p << 5) + col, n - 1);
        #pragma unroll
        for (int k = 0; k < K2; ++k)
            ci[k] = __builtin_nontemporal_load(nidx + (size_t)k * n + vc);
    }

    for (;;) {
        const int vbase = p << 5;
        const int vc = min(vbase + col, n - 1);

        // residual x row (coalesced, streamed once -> nt)
        const f32x4* xr = (const f32x4*)(x + (size_t)vc * CIN + half * 8);
        const f32x4 xa = __builtin_nontemporal_load(xr);
        const f32x4 xb = __builtin_nontemporal_load(xr + 1);

        // issue all 9 h-row gathers straight into A-frags (unconditional)
        bf16x8 A0[K2], A1[K2];
        #pragma unroll
        for (int k = 0; k < K2; ++k) {
            const char* pg = (const char*)hbuf + (size_t)(uint32_t)ci[k] * (COUT * 2);
            A0[k] = *(const bf16x8*)(pg + half * 16);
            A1[k] = *(const bf16x8*)(pg + 32 + half * 16);
        }

        // masks load concurrently with the gathers
        int mk[K2];
        #pragma unroll
        for (int k = 0; k < K2; ++k) {
            const size_t e = (size_t)k * n + (size_t)vc;
            mk[k] = mode32 ? __builtin_nontemporal_load(m32 + e)
                           : (int)__builtin_nontemporal_load(m8 + e);
        }

        // prefetch next-tile indices (ci dead after gather issue)
        const int pn = p + stride;
        {
            const int pc = (pn < ntiles) ? pn : p;
            const int wc = min((pc << 5) + col, n - 1);
            #pragma unroll
            for (int k = 0; k < K2; ++k)
                ci[k] = __builtin_nontemporal_load(nidx + (size_t)k * n + wc);
        }

        f32x16 acc = {};

        // residual x @ Wp, hi/lo split (effectively f32-accurate)
        {
            const bf16x8 Bp = *(const bf16x8*)&smw[K2 * 4 * 32 * 8 + (half * 32 + col) * 8];
            bf16x8 hi, lo;
            #pragma unroll
            for (int e = 0; e < 8; ++e) {
                const float xv = (e < 4) ? xa[e] : xb[e - 4];
                const uint16_t hb = f2bf(xv);
                hi[e] = (short)hb;
                lo[e] = (short)f2bf(xv - bf2f(hb));
            }
            acc = __builtin_amdgcn_mfma_f32_32x32x16_bf16(hi, Bp, acc, 0, 0, 0);
            acc = __builtin_amdgcn_mfma_f32_32x32x16_bf16(lo, Bp, acc, 0, 0, 0);
        }

        #pragma unroll
        for (int k = 0; k < K2; ++k) {
            const bf16x8 B0 = *(const bf16x8*)&smw[(((k * 2 + 0) * 2 + half) * 32 + col) * 8];
            const bf16x8 B1 = *(const bf16x8*)&smw[(((k * 2 + 1) * 2 + half) * 32 + col) * 8];
            const bf16x8 zf = {};
            const bool m = mk[k] != 0;
            const bf16x8 a0 = m ? A0[k] : zf;
            const bf16x8 a1 = m ? A1[k] : zf;
            acc = __builtin_amdgcn_mfma_f32_32x32x16_bf16(a0, B0, acc, 0, 0, 0);
            acc = __builtin_amdgcn_mfma_f32_32x32x16_bf16(a1, B1, acc, 0, 0, 0);
        }

        #pragma unroll
        for (int r = 0; r < 16; ++r) {
            const int row = (r & 3) + 8 * (r >> 2) + 4 * half;
            const int vo = vbase + row;
            if (vo < n)
                __builtin_nontemporal_store(fmaxf(acc[r] + bias, 0.0f),
                                            out + (size_t)vo * COUT + col);
        }

        if (pn >= ntiles) break;
        p = pn;
    }
}

extern "C" void kernel_launch(void* const* d_in, const int* in_sizes, int n_in,
                              void* d_out, int out_size, void* d_ws, size_t ws_size,
                              hipStream_t stream) {
    const float* x    = (const float*)d_in[0];
    const float* W1   = (const float*)d_in[1];
    const float* b1   = (const float*)d_in[2];
    const float* W2   = (const float*)d_in[3];
    const float* b2   = (const float*)d_in[4];
    const float* Wp   = (const float*)d_in[5];
    const float* bp   = (const float*)d_in[6];
    const int*   nidx = (const int*)d_in[7];
    const void*  nmask = d_in[8];
    const int n = in_sizes[0] / CIN;

    int*      mflag = (int*)d_ws;                       // [0,4): mask-mode flag
    uint16_t* hbuf  = (uint16_t*)((char*)d_ws + 256);   // bf16 h [n][32]

    detect_mask_kernel<<<1, 64, 0, stream>>>((const uint32_t*)nmask, mflag, n);

    const int ntiles = (n + 31) / 32;
    int grid = (ntiles + 3) / 4;
    if (grid > 2048) grid = 2048;

    conv1_kernel<<<grid, 256, 0, stream>>>(x, W1, b1, nidx, nmask, mflag, hbuf, n);
    conv2_kernel<<<grid, 256, 0, stream>>>(x, W2, b2, Wp, bp, nidx, nmask, mflag,
                                           hbuf, (float*)d_out, n);
}